// Round 16
// baseline (45.739 us; speedup 1.0000x reference)
//
#include <hip/hip_runtime.h>
#include <stdint.h>
#include <type_traits>

// DCN forward: B=4, H=128, W=128, G=8, C=32, K=8
// inputs      [B,H,W,G,C]   fp32
// deformables [B,H,W,G,K,2] fp32
// weights     [B,H,W,G,K]   fp32
// out         [B,H,W,G,C]   fp32
//
// R16 = R15 with 256-thread blocks for cross-block latency overlap:
//  - 8x8 px tile, 4 lanes/px; RH=4 halo -> 16x16 cells x 80 B = 20480 B LDS
//    -> 8 blocks/CU (= 32 waves, 100% headroom; R15 had 4 blocks x 8 waves
//    and measured only 37.6% occupancy -- block staging/barrier/tail gaps).
//  - window 16x16 is pow2: staging index = shift/mask, exactly 4 rounds.
//  - keeps: v_fma_mix_f32 asm (1 inst/channel, exact f32 fma), CUNITS=5,
//    coalesced (cell,unit)-linear staging, interior mask-elision,
//    unclamped-index == staging-clamp equivalence, exact f32 fallback.

#define Bc 4
#define Hc 128
#define Wc 128
#define Gc 8
#define Kc 8
#define TH 8
#define TW 8
#define RH 4
#define WN 16             // 16x16 cell window
#define NCELL (WN*WN)     // 256
#define CUNITS 5          // 16B units per cell (80 B; 64 B data + 16 pad)

typedef float    float4v __attribute__((ext_vector_type(4)));
typedef _Float16 half8v  __attribute__((ext_vector_type(8)));
typedef uint32_t uint4v  __attribute__((ext_vector_type(4)));

union PkU { half8v h; uint4v u; };

// acc += (f16 lo/hi of PK) * C   -- exact f32 fma, f16 converted exactly
#define FMA_MIX_LO(ACC, PK, C) \
    asm("v_fma_mix_f32 %0, %1, %2, %0 op_sel:[0,0,0] op_sel_hi:[1,0,0]" \
        : "+v"(ACC) : "v"(PK), "v"(C))
#define FMA_MIX_HI(ACC, PK, C) \
    asm("v_fma_mix_f32 %0, %1, %2, %0 op_sel:[1,0,0] op_sel_hi:[1,0,0]" \
        : "+v"(ACC) : "v"(PK), "v"(C))

__global__ __launch_bounds__(256, 8) void dcn_fwd(
    const float* __restrict__ inp,
    const float* __restrict__ def,
    const float* __restrict__ wts,
    float* __restrict__ out)
{
    const int tid = threadIdx.x;
    const int j   = tid & 3;       // lane owns channels 8j..8j+7 (one 16B unit)
    const int px  = tid >> 2;      // 0..63 pixel in tile
    const int pw  = px & 7;
    const int ph  = px >> 3;

    // grid: wt(16), ht(16), g(8), b(4)
    const int blk = blockIdx.x;
    const int wt = blk & 15;
    const int ht = (blk >> 4) & 15;
    const int g  = (blk >> 8) & 7;
    const int b  = blk >> 11;

    const int h0 = ht * TH, w0 = wt * TW;
    const int row0 = h0 - RH, col0 = w0 - RH;   // window origin (may be <0)

    // global plane as float4 units: index = y*8192 + x*64 + u
    const float4v* gp4 = (const float4v*)((const char*)inp
        + ((size_t)b << 24) + ((size_t)g << 7));

    __shared__ uint4v tile[NCELL * CUNITS];   // 20480 B

    const int h = h0 + ph;
    const int w = w0 + pw;
    const int pg = ((b * Hc + h) * Wc + w) * Gc + g;

    // per-pixel def/wts (4 lanes load same addr; coalescer merges)
    const float4v d0 = *(const float4v*)(def + (size_t)pg * 16 + 0);
    const float4v d1 = *(const float4v*)(def + (size_t)pg * 16 + 4);
    const float4v d2 = *(const float4v*)(def + (size_t)pg * 16 + 8);
    const float4v d3 = *(const float4v*)(def + (size_t)pg * 16 + 12);
    const float4v q0 = *(const float4v*)(wts + (size_t)pg * 8 + 0);
    const float4v q1 = *(const float4v*)(wts + (size_t)pg * 8 + 4);

    // ---- stage 16x16 cell window as f16 (RTE): linear (cell,u2), coalesced ----
    // 256 cells x 4 units = 1024 writes; exactly 4 rounds of 256.
#pragma unroll
    for (int r = 0; r < 4; ++r) {
        const int idx  = r * 256 + tid;
        const int cell = idx >> 2;
        const int u2   = idx & 3;
        const int rr   = cell >> 4;
        const int cc   = cell & 15;
        const int gr   = min(max(row0 + rr, 0), Hc - 1);
        const int gc   = min(max(col0 + cc, 0), Wc - 1);
        const float4v* src = &gp4[gr * 8192 + gc * 64 + u2 * 2];
        const float4v a = src[0];
        const float4v c = src[1];
        PkU p;
        p.h = (half8v){(_Float16)a.x, (_Float16)a.y, (_Float16)a.z, (_Float16)a.w,
                       (_Float16)c.x, (_Float16)c.y, (_Float16)c.z, (_Float16)c.w};
        tile[cell * CUNITS + u2] = p.u;
    }
    __syncthreads();

    const float dxs[8] = {d0.x, d0.z, d1.x, d1.z, d2.x, d2.z, d3.x, d3.z};
    const float dys[8] = {d0.y, d0.w, d1.y, d1.w, d2.y, d2.w, d3.y, d3.w};
    const float wks[8] = {q0.x, q0.y, q0.z, q0.w, q1.x, q1.y, q1.z, q1.w};

    const float wf = (float)w;
    const float hf = (float)h;

    float acc[8];
#pragma unroll
    for (int i = 0; i < 8; ++i) acc[i] = 0.f;

    auto kloop = [&](auto masked_t) {
        constexpr bool MASKED = decltype(masked_t)::value;
#pragma unroll
        for (int k = 0; k < Kc; ++k) {
            const float dx = dxs[k];
            const float dy = dys[k];
            const float wk = wks[k];

            const float x = dx + wf;
            const float y = dy + hf;

            // truncation toward zero, matching .astype(int32)
            const int fx = (int)x;
            const int fy = (int)y;

            const float wx1 = x - (float)fx;   // exact
            const float wy1 = y - (float)fy;
            const float wx0 = 1.0f - wx1;      // == cxf - x
            const float wy0 = 1.0f - wy1;

            const bool inh = (fabsf(dx) < 4.0f) & (fabsf(dy) < 4.0f);
            if (__builtin_expect(inh, 1)) {
                float ax0 = wx0, ax1 = wx1, ay0 = wy0, ay1 = wy1;
                if constexpr (MASKED) {
                    ax0 = ((uint32_t)fx       < (uint32_t)Wc) ? wx0 : 0.f;
                    ax1 = ((uint32_t)(fx + 1) < (uint32_t)Wc) ? wx1 : 0.f;
                    ay0 = ((uint32_t)fy       < (uint32_t)Hc) ? wy0 : 0.f;
                    ay1 = ((uint32_t)(fy + 1) < (uint32_t)Hc) ? wy1 : 0.f;
                }
                const float ay0k = wk * ay0;
                const float ay1k = wk * ay1;
                const float c00 = ay0k * ax0;
                const float c01 = ay0k * ax1;
                const float c10 = ay1k * ax0;
                const float c11 = ay1k * ax1;

                // unclamped fx,fy valid in-window (|d|<4); staging clamp
                // already equals the reference image clamp.
                const int iu = (((fy - row0) << 4) + (fx - col0)) * CUNITS + j;
                const uint4v v00 = tile[iu];                      // (x  ,y  )
                const uint4v v01 = tile[iu + CUNITS];             // (x+1,y  )
                const uint4v v10 = tile[iu + WN * CUNITS];        // (x  ,y+1)
                const uint4v v11 = tile[iu + (WN + 1) * CUNITS];  // (x+1,y+1)

                FMA_MIX_LO(acc[0], v00.x, c00); FMA_MIX_HI(acc[1], v00.x, c00);
                FMA_MIX_LO(acc[2], v00.y, c00); FMA_MIX_HI(acc[3], v00.y, c00);
                FMA_MIX_LO(acc[4], v00.z, c00); FMA_MIX_HI(acc[5], v00.z, c00);
                FMA_MIX_LO(acc[6], v00.w, c00); FMA_MIX_HI(acc[7], v00.w, c00);

                FMA_MIX_LO(acc[0], v01.x, c01); FMA_MIX_HI(acc[1], v01.x, c01);
                FMA_MIX_LO(acc[2], v01.y, c01); FMA_MIX_HI(acc[3], v01.y, c01);
                FMA_MIX_LO(acc[4], v01.z, c01); FMA_MIX_HI(acc[5], v01.z, c01);
                FMA_MIX_LO(acc[6], v01.w, c01); FMA_MIX_HI(acc[7], v01.w, c01);

                FMA_MIX_LO(acc[0], v10.x, c10); FMA_MIX_HI(acc[1], v10.x, c10);
                FMA_MIX_LO(acc[2], v10.y, c10); FMA_MIX_HI(acc[3], v10.y, c10);
                FMA_MIX_LO(acc[4], v10.z, c10); FMA_MIX_HI(acc[5], v10.z, c10);
                FMA_MIX_LO(acc[6], v10.w, c10); FMA_MIX_HI(acc[7], v10.w, c10);

                FMA_MIX_LO(acc[0], v11.x, c11); FMA_MIX_HI(acc[1], v11.x, c11);
                FMA_MIX_LO(acc[2], v11.y, c11); FMA_MIX_HI(acc[3], v11.y, c11);
                FMA_MIX_LO(acc[4], v11.z, c11); FMA_MIX_HI(acc[5], v11.z, c11);
                FMA_MIX_LO(acc[6], v11.w, c11); FMA_MIX_HI(acc[7], v11.w, c11);
            } else {
                // rare (P~1e-4): exact f32 global gather, true reference clamps
                const float ax0 = ((uint32_t)fx       < (uint32_t)Wc) ? wx0 : 0.f;
                const float ax1 = ((uint32_t)(fx + 1) < (uint32_t)Wc) ? wx1 : 0.f;
                const float ay0 = ((uint32_t)fy       < (uint32_t)Hc) ? wy0 : 0.f;
                const float ay1 = ((uint32_t)(fy + 1) < (uint32_t)Hc) ? wy1 : 0.f;
                const int xf = min(max(fx,     0), Wc - 1);
                const int xc = min(max(fx + 1, 0), Wc - 1);
                const int yf = min(max(fy,     0), Hc - 1);
                const int yc = min(max(fy + 1, 0), Hc - 1);
                const float ay0k = wk * ay0;
                const float ay1k = wk * ay1;
                const float c00 = ay0k * ax0;
                const float c01 = ay0k * ax1;
                const float c10 = ay1k * ax0;
                const float c11 = ay1k * ax1;
                const float4v* p00 = &gp4[yf * 8192 + xf * 64 + 2 * j];
                const float4v* p01 = &gp4[yf * 8192 + xc * 64 + 2 * j];
                const float4v* p10 = &gp4[yc * 8192 + xf * 64 + 2 * j];
                const float4v* p11 = &gp4[yc * 8192 + xc * 64 + 2 * j];
#pragma unroll
                for (int u2 = 0; u2 < 2; ++u2) {
                    const float4v a = p00[u2], bb = p01[u2];
                    const float4v c = p10[u2], dd = p11[u2];
#pragma unroll
                    for (int e = 0; e < 4; ++e) {
                        float s = acc[u2 * 4 + e];
                        s = fmaf(a[e],  c00, s);
                        s = fmaf(bb[e], c01, s);
                        s = fmaf(c[e],  c10, s);
                        s = fmaf(dd[e], c11, s);
                        acc[u2 * 4 + e] = s;
                    }
                }
            }
        }
    };

    // interior tiles: in-halo corners provably in-image -> masks all 1
    const bool interior = ((uint32_t)(wt - 1) <= 13u) & ((uint32_t)(ht - 1) <= 13u);
    if (interior) kloop(std::integral_constant<bool, false>{});
    else          kloop(std::integral_constant<bool, true>{});

    // channels 8j..8j+7 = float4 units 2j, 2j+1 (32 B contiguous)
    float4v* op = (float4v*)((char*)out + (size_t)pg * 128) + 2 * j;
    float4v o0 = {acc[0], acc[1], acc[2], acc[3]};
    float4v o1 = {acc[4], acc[5], acc[6], acc[7]};
    op[0] = o0;
    op[1] = o1;
}

extern "C" void kernel_launch(void* const* d_in, const int* in_sizes, int n_in,
                              void* d_out, int out_size, void* d_ws, size_t ws_size,
                              hipStream_t stream) {
    const float* inp = (const float*)d_in[0];
    const float* def = (const float*)d_in[1];
    const float* wts = (const float*)d_in[2];
    float* out = (float*)d_out;

    const int nblocks = Bc * Gc * (Hc / TH) * (Wc / TW);  // 8192
    dcn_fwd<<<nblocks, 256, 0, stream>>>(inp, def, wts, out);
}

// Round 17
// 43.357 us; speedup vs baseline: 1.0550x; 1.0550x over previous
//
#include <hip/hip_runtime.h>
#include <stdint.h>
#include <type_traits>

// DCN forward: B=4, H=128, W=128, G=8, C=32, K=8
// inputs      [B,H,W,G,C]   fp32
// deformables [B,H,W,G,K,2] fp32
// weights     [B,H,W,G,K]   fp32
// out         [B,H,W,G,C]   fp32
//
// R17 = R15 (best, 43.5us) with the bank-conflict layout fix:
//  - CUNITS=4 (64B cells, no pad): pixel's 4 lanes occupy granules
//    {4c..4c+3} mod 8 = one bank-half, parity(c) selects which.
//  - WN=25 (odd): phase partner pixels' cell delta = 25*dfy+dfx has parity
//    dfy+dfx -> the dominant neighbor cases (+-1,0),(0,+-1) land in OPPOSITE
//    halves = conflict-free. (Old CUNITS=5/WN=24: ~89% of phases collided.)
//  - LDS 16x25x64 = 25.6 KB; *4 index = shift; staging write phases = 2
//    consecutive cells = opposite parity = conflict-free.
//  - keeps: 8x16 px tile, 512 thr, 4 lanes/px, v_fma_mix_f32 asm, RH=4,
//    coalesced staging, interior mask-elision, unclamped-index ==
//    staging-clamp equivalence, exact f32 fallback (P~1e-4).

#define Bc 4
#define Hc 128
#define Wc 128
#define Gc 8
#define Kc 8
#define TH 8
#define TW 16
#define RH 4
#define WR 16             // window rows = TH + 2*RH
#define WN 25             // window cols (24 used + 1 pad col, ODD for parity)
#define NCELL (WR*WN)     // 400
#define CUNITS 4          // 16B units per cell (64 B, no pad)

typedef float    float4v __attribute__((ext_vector_type(4)));
typedef _Float16 half8v  __attribute__((ext_vector_type(8)));
typedef uint32_t uint4v  __attribute__((ext_vector_type(4)));

union PkU { half8v h; uint4v u; };

// acc += (f16 lo/hi of PK) * C   -- exact f32 fma, f16 converted exactly
#define FMA_MIX_LO(ACC, PK, C) \
    asm("v_fma_mix_f32 %0, %1, %2, %0 op_sel:[0,0,0] op_sel_hi:[1,0,0]" \
        : "+v"(ACC) : "v"(PK), "v"(C))
#define FMA_MIX_HI(ACC, PK, C) \
    asm("v_fma_mix_f32 %0, %1, %2, %0 op_sel:[1,0,0] op_sel_hi:[1,0,0]" \
        : "+v"(ACC) : "v"(PK), "v"(C))

__global__ __launch_bounds__(512, 4) void dcn_fwd(
    const float* __restrict__ inp,
    const float* __restrict__ def,
    const float* __restrict__ wts,
    float* __restrict__ out)
{
    const int tid = threadIdx.x;
    const int j   = tid & 3;       // lane owns channels 8j..8j+7 (one 16B unit)
    const int px  = tid >> 2;      // 0..127 pixel in tile
    const int pw  = px & 15;
    const int ph  = px >> 4;

    // grid: wt(8), ht(16), g(8), b(4)
    const int blk = blockIdx.x;
    const int wt = blk & 7;
    const int ht = (blk >> 3) & 15;
    const int g  = (blk >> 7) & 7;
    const int b  = blk >> 10;

    const int h0 = ht * TH, w0 = wt * TW;
    const int row0 = h0 - RH, col0 = w0 - RH;   // window origin (may be <0)

    // global plane as float4 units: index = y*8192 + x*64 + u
    const float4v* gp4 = (const float4v*)((const char*)inp
        + ((size_t)b << 24) + ((size_t)g << 7));

    __shared__ uint4v tile[NCELL * CUNITS];   // 25600 B

    const int h = h0 + ph;
    const int w = w0 + pw;
    const int pg = ((b * Hc + h) * Wc + w) * Gc + g;

    // per-pixel def/wts (4 lanes load same addr; coalescer merges)
    const float4v d0 = *(const float4v*)(def + (size_t)pg * 16 + 0);
    const float4v d1 = *(const float4v*)(def + (size_t)pg * 16 + 4);
    const float4v d2 = *(const float4v*)(def + (size_t)pg * 16 + 8);
    const float4v d3 = *(const float4v*)(def + (size_t)pg * 16 + 12);
    const float4v q0 = *(const float4v*)(wts + (size_t)pg * 8 + 0);
    const float4v q1 = *(const float4v*)(wts + (size_t)pg * 8 + 4);

    // ---- stage 16x25 cell window as f16 (RTE): linear (cell,u2), coalesced ----
    // 400 cells x 4 units = 1600 writes; 4 rounds of 512 (last partial).
#pragma unroll
    for (int r = 0; r < 4; ++r) {
        const int idx = r * 512 + tid;
        if (idx < NCELL * CUNITS) {
            const int cell = idx >> 2;
            const int u2   = idx & 3;
            const int rr   = (cell * 2622) >> 16;    // exact cell/25, cell<400
            const int cc   = cell - rr * WN;
            const int gr   = min(max(row0 + rr, 0), Hc - 1);
            const int gc   = min(max(col0 + cc, 0), Wc - 1);
            const float4v* src = &gp4[gr * 8192 + gc * 64 + u2 * 2];
            const float4v a = src[0];
            const float4v c = src[1];
            PkU p;
            p.h = (half8v){(_Float16)a.x, (_Float16)a.y, (_Float16)a.z, (_Float16)a.w,
                           (_Float16)c.x, (_Float16)c.y, (_Float16)c.z, (_Float16)c.w};
            tile[(cell << 2) + u2] = p.u;
        }
    }
    __syncthreads();

    const float dxs[8] = {d0.x, d0.z, d1.x, d1.z, d2.x, d2.z, d3.x, d3.z};
    const float dys[8] = {d0.y, d0.w, d1.y, d1.w, d2.y, d2.w, d3.y, d3.w};
    const float wks[8] = {q0.x, q0.y, q0.z, q0.w, q1.x, q1.y, q1.z, q1.w};

    const float wf = (float)w;
    const float hf = (float)h;

    float acc[8];
#pragma unroll
    for (int i = 0; i < 8; ++i) acc[i] = 0.f;

    auto kloop = [&](auto masked_t) {
        constexpr bool MASKED = decltype(masked_t)::value;
#pragma unroll
        for (int k = 0; k < Kc; ++k) {
            const float dx = dxs[k];
            const float dy = dys[k];
            const float wk = wks[k];

            const float x = dx + wf;
            const float y = dy + hf;

            // truncation toward zero, matching .astype(int32)
            const int fx = (int)x;
            const int fy = (int)y;

            const float wx1 = x - (float)fx;   // exact
            const float wy1 = y - (float)fy;
            const float wx0 = 1.0f - wx1;      // == cxf - x
            const float wy0 = 1.0f - wy1;

            const bool inh = (fabsf(dx) < 4.0f) & (fabsf(dy) < 4.0f);
            if (__builtin_expect(inh, 1)) {
                float ax0 = wx0, ax1 = wx1, ay0 = wy0, ay1 = wy1;
                if constexpr (MASKED) {
                    ax0 = ((uint32_t)fx       < (uint32_t)Wc) ? wx0 : 0.f;
                    ax1 = ((uint32_t)(fx + 1) < (uint32_t)Wc) ? wx1 : 0.f;
                    ay0 = ((uint32_t)fy       < (uint32_t)Hc) ? wy0 : 0.f;
                    ay1 = ((uint32_t)(fy + 1) < (uint32_t)Hc) ? wy1 : 0.f;
                }
                const float ay0k = wk * ay0;
                const float ay1k = wk * ay1;
                const float c00 = ay0k * ax0;
                const float c01 = ay0k * ax1;
                const float c10 = ay1k * ax0;
                const float c11 = ay1k * ax1;

                // unclamped fx,fy valid in-window (|d|<4); staging clamp
                // already equals the reference image clamp.
                const int iu = (((fy - row0) * WN + (fx - col0)) << 2) + j;
                const uint4v v00 = tile[iu];                           // (x  ,y  )
                const uint4v v01 = tile[iu + CUNITS];                  // (x+1,y  )
                const uint4v v10 = tile[iu + WN * CUNITS];             // (x  ,y+1)
                const uint4v v11 = tile[iu + (WN + 1) * CUNITS];       // (x+1,y+1)

                FMA_MIX_LO(acc[0], v00.x, c00); FMA_MIX_HI(acc[1], v00.x, c00);
                FMA_MIX_LO(acc[2], v00.y, c00); FMA_MIX_HI(acc[3], v00.y, c00);
                FMA_MIX_LO(acc[4], v00.z, c00); FMA_MIX_HI(acc[5], v00.z, c00);
                FMA_MIX_LO(acc[6], v00.w, c00); FMA_MIX_HI(acc[7], v00.w, c00);

                FMA_MIX_LO(acc[0], v01.x, c01); FMA_MIX_HI(acc[1], v01.x, c01);
                FMA_MIX_LO(acc[2], v01.y, c01); FMA_MIX_HI(acc[3], v01.y, c01);
                FMA_MIX_LO(acc[4], v01.z, c01); FMA_MIX_HI(acc[5], v01.z, c01);
                FMA_MIX_LO(acc[6], v01.w, c01); FMA_MIX_HI(acc[7], v01.w, c01);

                FMA_MIX_LO(acc[0], v10.x, c10); FMA_MIX_HI(acc[1], v10.x, c10);
                FMA_MIX_LO(acc[2], v10.y, c10); FMA_MIX_HI(acc[3], v10.y, c10);
                FMA_MIX_LO(acc[4], v10.z, c10); FMA_MIX_HI(acc[5], v10.z, c10);
                FMA_MIX_LO(acc[6], v10.w, c10); FMA_MIX_HI(acc[7], v10.w, c10);

                FMA_MIX_LO(acc[0], v11.x, c11); FMA_MIX_HI(acc[1], v11.x, c11);
                FMA_MIX_LO(acc[2], v11.y, c11); FMA_MIX_HI(acc[3], v11.y, c11);
                FMA_MIX_LO(acc[4], v11.z, c11); FMA_MIX_HI(acc[5], v11.z, c11);
                FMA_MIX_LO(acc[6], v11.w, c11); FMA_MIX_HI(acc[7], v11.w, c11);
            } else {
                // rare (P~1e-4): exact f32 global gather, true reference clamps
                const float ax0 = ((uint32_t)fx       < (uint32_t)Wc) ? wx0 : 0.f;
                const float ax1 = ((uint32_t)(fx + 1) < (uint32_t)Wc) ? wx1 : 0.f;
                const float ay0 = ((uint32_t)fy       < (uint32_t)Hc) ? wy0 : 0.f;
                const float ay1 = ((uint32_t)(fy + 1) < (uint32_t)Hc) ? wy1 : 0.f;
                const int xf = min(max(fx,     0), Wc - 1);
                const int xc = min(max(fx + 1, 0), Wc - 1);
                const int yf = min(max(fy,     0), Hc - 1);
                const int yc = min(max(fy + 1, 0), Hc - 1);
                const float ay0k = wk * ay0;
                const float ay1k = wk * ay1;
                const float c00 = ay0k * ax0;
                const float c01 = ay0k * ax1;
                const float c10 = ay1k * ax0;
                const float c11 = ay1k * ax1;
                const float4v* p00 = &gp4[yf * 8192 + xf * 64 + 2 * j];
                const float4v* p01 = &gp4[yf * 8192 + xc * 64 + 2 * j];
                const float4v* p10 = &gp4[yc * 8192 + xf * 64 + 2 * j];
                const float4v* p11 = &gp4[yc * 8192 + xc * 64 + 2 * j];
#pragma unroll
                for (int u2 = 0; u2 < 2; ++u2) {
                    const float4v a = p00[u2], bb = p01[u2];
                    const float4v c = p10[u2], dd = p11[u2];
#pragma unroll
                    for (int e = 0; e < 4; ++e) {
                        float s = acc[u2 * 4 + e];
                        s = fmaf(a[e],  c00, s);
                        s = fmaf(bb[e], c01, s);
                        s = fmaf(c[e],  c10, s);
                        s = fmaf(dd[e], c11, s);
                        acc[u2 * 4 + e] = s;
                    }
                }
            }
        }
    };

    // interior tiles: in-halo corners provably in-image -> masks all 1
    const bool interior = ((uint32_t)(wt - 1) <= 5u) & ((uint32_t)(ht - 1) <= 13u);
    if (interior) kloop(std::integral_constant<bool, false>{});
    else          kloop(std::integral_constant<bool, true>{});

    // channels 8j..8j+7 = float4 units 2j, 2j+1 (32 B contiguous)
    float4v* op = (float4v*)((char*)out + (size_t)pg * 128) + 2 * j;
    float4v o0 = {acc[0], acc[1], acc[2], acc[3]};
    float4v o1 = {acc[4], acc[5], acc[6], acc[7]};
    op[0] = o0;
    op[1] = o1;
}

extern "C" void kernel_launch(void* const* d_in, const int* in_sizes, int n_in,
                              void* d_out, int out_size, void* d_ws, size_t ws_size,
                              hipStream_t stream) {
    const float* inp = (const float*)d_in[0];
    const float* def = (const float*)d_in[1];
    const float* wts = (const float*)d_in[2];
    float* out = (float*)d_out;

    const int nblocks = Bc * Gc * (Hc / TH) * (Wc / TW);  // 4096
    dcn_fwd<<<nblocks, 512, 0, stream>>>(inp, def, wts, out);
}